// Round 9
// baseline (170.169 us; speedup 1.0000x reference)
//
#include <hip/hip_runtime.h>

// SNNLinear, exact-trajectory i8-digit MFMA. Round 27 = plane-split +
// VGPR-lean inner loop (A ping-pong) + LDS pad.
// R26 post-mortem: at 4 waves/SIMD the allocator splits the unified file
// 64 VGPR / 64 AGPR. acc[7][2]=56 fits AGPR, but af[7](28)+b(8)+addr+
// epilogue overran the 64-VGPR side -> in-loop spill (WRITE 101 MB,
// VGPR_Count=64). Plus 49K LDS bank conflicts from 128B-stride i64 rows.
// R27:
//   - inner loop keeps only TWO A registers live (a0/a1 ping-pong, all
//     compile-time indices): load a(i+1) during a(i)'s 2 MFMAs. Loop
//     VGPR high-water ~26. 4 decorrelated waves/SIMD cover the chain.
//   - LDS row padded 16->17 (i64): partial store / merge read / du store
//     all conflict-free; scan reads 2-way (free).
//   - epilogue exact combine v = v0 + 2^16*v1 (i64, |v|<2^42) -> exact
//     f64 du -> f64 scan verbatim (R16 math).
// Structure: block = 128 thr = 2 waves, one (b,ng) task; wave w computes
// planes {2w,2w+1}; launch_bounds(128,4) -> 4 waves/SIMD, 8 blocks/CU
// (LDS 13.6KB x 8 = 109KB). bid = ng*64 + b -> same-CU blocks share the
// A panel (L1/L2) and bid%8=b%8 gives XCD locality.
// Math identical to R19..R26 (all passed).
// Outputs: ss[100,64,1024] | mem_out[64,1024] | hat_s[64,1024]
// ws: [0, 7.34M) A8 (b-major, kt-contiguous) ; [7.34M, 11.53M) Bt (4 planes)

typedef __attribute__((ext_vector_type(4))) int int4v;

#define T_STEPS 100
#define T_PAD   112
#define BO      65536
#define K_DIM   1024
#define A8_OFF  0
#define BT_OFF  7340032      // 64*112*1024
#define ROW     17           // padded LDS row (i64/f64 elems)

// ---- prepass (R24 verbatim): spikes -> A8 (b-major, kt-contiguous tiles);
//               W -> Bt 4 balanced base-256 i8 planes ----
__global__ __launch_bounds__(256)
void prepass(const float* __restrict__ S, const float* __restrict__ W,
             signed char* __restrict__ A8, signed char* __restrict__ Bt) {
    const int wave = blockIdx.x * 4 + (threadIdx.x >> 6);  // 0..8191
    const int lane = threadIdx.x & 63;
    const int r16 = lane & 15, quad = lane >> 4;

    if (wave < 7168) {
        // A tile: wave = b*112 + jt*16 + k64 ; rows t = jt*16 + r16
        const int b   = wave / 112;
        const int rem = wave - b * 112;
        const int jt  = rem >> 4, k64 = rem & 15;
        const int t   = jt * 16 + r16;
        union { signed char c[16]; int4v v; } u;
        if (t < T_STEPS) {
            const float* sp = S + ((size_t)t * 64 + b) * K_DIM + k64 * 64 + quad * 16;
            const float4 s0 = *(const float4*)(sp);
            const float4 s1 = *(const float4*)(sp + 4);
            const float4 s2 = *(const float4*)(sp + 8);
            const float4 s3 = *(const float4*)(sp + 12);
            const float sv[16] = {s0.x,s0.y,s0.z,s0.w, s1.x,s1.y,s1.z,s1.w,
                                  s2.x,s2.y,s2.z,s2.w, s3.x,s3.y,s3.z,s3.w};
#pragma unroll
            for (int e = 0; e < 16; ++e) u.c[e] = (signed char)sv[e];  // exact 0/1
        } else {
#pragma unroll
            for (int e = 0; e < 16; ++e) u.c[e] = 0;                   // t-pad
        }
        // kt-contiguous chunk index: k64*7 + jt
        *(int4v*)(A8 + ((size_t)(b * 112 + k64 * 7 + jt)) * 1024 + lane * 16) = u.v;
    } else {
        const int t2 = wave - 7168;                 // 0..1023
        const int n16 = t2 >> 4, k64 = t2 & 15;
        const int n = n16 * 16 + r16;
        const float* wp = W + (size_t)n * K_DIM + k64 * 64 + quad * 16;
        const float4 w0 = *(const float4*)(wp);
        const float4 w1 = *(const float4*)(wp + 4);
        const float4 w2 = *(const float4*)(wp + 8);
        const float4 w3 = *(const float4*)(wp + 12);
        const float wv[16] = {w0.x,w0.y,w0.z,w0.w, w1.x,w1.y,w1.z,w1.w,
                              w2.x,w2.y,w2.z,w2.w, w3.x,w3.y,w3.z,w3.w};
        union { signed char c[16]; int4v v; } u[4];
#pragma unroll
        for (int e = 0; e < 16; ++e) {
            long long q = llrint((double)wv[e] * 0x1p28);   // |q| < 2^31
#pragma unroll
            for (int p = 0; p < 3; ++p) {
                const int d = (int)(((q + 128) & 255) - 128);  // [-128,127]
                u[p].c[e] = (signed char)d;
                q = (q - d) >> 8;                              // exact
            }
            u[3].c[e] = (signed char)q;                        // |d3| <= ~88
        }
        signed char* base = Bt + (size_t)(n16 * 16 + k64) * 4 * 1024 + lane * 16;
#pragma unroll
        for (int p = 0; p < 4; ++p)
            *(int4v*)(base + (size_t)p * 1024) = u[p].v;
    }
}

// two MFMAs of one A fragment against both live planes
#define MM(I, AREG)                                                           \
    acc[I][0] = __builtin_amdgcn_mfma_i32_16x16x64_i8(AREG, b0, acc[I][0], 0, 0, 0); \
    acc[I][1] = __builtin_amdgcn_mfma_i32_16x16x64_i8(AREG, b1, acc[I][1], 0, 0, 0);

// ---- fused GEMM + scan: 2 waves/block, plane-split, 4 waves/SIMD. ----
__global__ __launch_bounds__(128, 4)
void gemm_scan(const signed char* __restrict__ A8,
               const signed char* __restrict__ Bt,
               const float* __restrict__ bias,
               const float* __restrict__ mem0,
               float* __restrict__ out) {
    __shared__ double dulds[T_STEPS * ROW];      // 13600 B; aliased i64 partials
    long long* llds = (long long*)dulds;

    const int bid = blockIdx.x;                  // 0..4095
    const int ng  = bid >> 6;                    // n16 tile 0..63
    const int b   = bid & 63;                    // bid%8 = b%8 -> XCD A-locality

    const int tid  = threadIdx.x;
    const int lane = tid & 63, wid = tid >> 6;   // wid w: planes {2w,2w+1}
    const int quad = lane >> 4, r16 = lane & 15;

    const signed char* abase = A8 + (size_t)b * T_PAD * 1024 + lane * 16;
    const signed char* bbase = Bt + (size_t)ng * 65536 + (size_t)wid * 2048 + lane * 16;

    int4v acc[7][2] = {};

    for (int kt = 0; kt < 16; ++kt) {
        const signed char* ak  = abase + (size_t)kt * 7168;
        const signed char* ak2 = ak + 4096;
        const signed char* bk  = bbase + (size_t)kt * 4096;
        const int4v b0 = *(const int4v*)(bk);
        const int4v b1 = *(const int4v*)(bk + 1024);
        int4v a0, a1;
        a0 = *(const int4v*)(ak);
        a1 = *(const int4v*)(ak + 1024);
        MM(0, a0);
        a0 = *(const int4v*)(ak + 2048);
        MM(1, a1);
        a1 = *(const int4v*)(ak + 3072);
        MM(2, a0);
        a0 = *(const int4v*)(ak2);
        MM(3, a1);
        a1 = *(const int4v*)(ak2 + 1024);
        MM(4, a0);
        a0 = *(const int4v*)(ak2 + 2048);
        MM(5, a1);
        MM(6, a0);
    }

    // partial Horner: wave1 stages v1 = d2 + 256*d3 (exact i64, padded rows)
    if (wid == 1) {
#pragma unroll
        for (int i = 0; i < 7; ++i)
#pragma unroll
            for (int e = 0; e < 4; ++e) {
                const int t = i * 16 + quad * 4 + e;
                if (t < T_STEPS)
                    llds[t * ROW + r16] =
                        (long long)acc[i][1][e] * 256 + (long long)acc[i][0][e];
            }
    }
    __syncthreads();
    if (wid == 0) {
        const double bd = (double)bias[ng * 16 + r16];
#pragma unroll
        for (int i = 0; i < 7; ++i)
#pragma unroll
            for (int e = 0; e < 4; ++e) {
                const int t = i * 16 + quad * 4 + e;
                if (t < T_STEPS) {
                    long long v =
                        (long long)acc[i][1][e] * 256 + (long long)acc[i][0][e];
                    v += llds[t * ROW + r16] << 16;     // + 2^16*(d2+256*d3)
                    dulds[t * ROW + r16] = (double)v * 0x1p-28 + bd;  // exact
                }
            }
    }
    __syncthreads();

    // membrane scan (R16 math verbatim, exact f64 du): wave0 lanes 0-15.
    if (wid == 0 && lane < 16) {
        const int bo = b * 1024 + ng * 16 + lane;
        double m = (double)mem0[bo];
        double cnt = 0.0;
        double d[4];
#pragma unroll
        for (int u = 0; u < 4; ++u) d[u] = dulds[u * ROW + lane];
        for (int g = 0; g < 25; ++g) {
            double dn[4];
            if (g + 1 < 25) {
#pragma unroll
                for (int u = 0; u < 4; ++u) dn[u] = dulds[((g + 1) * 4 + u) * ROW + lane];
            }
#pragma unroll
            for (int u = 0; u < 4; ++u) {
                m += d[u];
                const double s = (m > 15.0) ? 1.0 : 0.0;
                m = fmin(fmax(m, 0.0), 15.0);
                out[(size_t)(g * 4 + u) * BO + bo] = (float)s;
                cnt += s;
                m -= m * s;
            }
            if (g + 1 < 25) {
#pragma unroll
                for (int u = 0; u < 4; ++u) d[u] = dn[u];
            }
        }
        out[(size_t)T_STEPS * BO + bo] = (float)m;
        out[(size_t)(T_STEPS + 1) * BO + bo] = (float)(cnt * 0.01);
    }
}

extern "C" void kernel_launch(void* const* d_in, const int* in_sizes, int n_in,
                              void* d_out, int out_size, void* d_ws, size_t ws_size,
                              hipStream_t stream) {
    const float* spikes = (const float*)d_in[0];  // [100,64,1024]
    const float* mem    = (const float*)d_in[1];  // [64,1024]
    // d_in[2] = hat_spikes: dead in forward
    const float* W      = (const float*)d_in[3];  // [1024,1024]
    const float* b      = (const float*)d_in[4];  // [1024]
    float* out = (float*)d_out;
    signed char* A8 = (signed char*)d_ws + A8_OFF;
    signed char* Bt = (signed char*)d_ws + BT_OFF;

    prepass<<<dim3(2048), 256, 0, stream>>>(spikes, W, A8, Bt);
    gemm_scan<<<dim3(4096), 128, 0, stream>>>(A8, Bt, b, mem, out);
}

// Round 10
// 145.364 us; speedup vs baseline: 1.1706x; 1.1706x over previous
//
#include <hip/hip_runtime.h>

// SNNLinear, exact-trajectory i8-digit MFMA. Round 28 = R27 with
// __launch_bounds__(128, 3)  (ONE variable changed).
// Allocator model (from R20-R27 evidence): with MFMA accs live, the
// compiler splits the unified gfx950 file at accum_offset ~ cap/2:
//   (64,2) cap256 -> 116 arch ok | (64,3) cap170 -> 84, acc112>86 SPILL
//   (128,4) cap128 -> 64, epilogue>64 SPILL | R18 (256,3): acc64<=85 &
//   arch~60<=84 -> FIT (why R18 never spilled).
// R27's plane-split acc[7][2]=56 fits the 86-AGPR half; its epilogue
// (~60 arch regs) fits the 84-arch half. R27's only fatal choice was
// cap 128. R28 = R27 @ (128,3): 3 waves/SIMD, 12 waves/CU, 6 blocks/CU
// (LDS 6x13.6KB=82KB). Per SIMD: 3 decorrelated waves x 286cy MFMA/kt
// ~= 858cy cover vs ~600cy fragment latency -> coverage >= 1 for the
// first time without spilling.
// Everything else BYTE-IDENTICAL to R27 (passed): b-major kt-contiguous
// A8, plane-split waves {2w,2w+1}, a0/a1 ping-pong inner loop, ROW=17
// padded LDS (0 bank conflicts), exact combine v = v0 + 2^16*v1,
// exact f64 du, R16-verbatim f64 scan.
// Outputs: ss[100,64,1024] | mem_out[64,1024] | hat_s[64,1024]
// ws: [0, 7.34M) A8 (b-major, kt-contiguous) ; [7.34M, 11.53M) Bt (4 planes)

typedef __attribute__((ext_vector_type(4))) int int4v;

#define T_STEPS 100
#define T_PAD   112
#define BO      65536
#define K_DIM   1024
#define A8_OFF  0
#define BT_OFF  7340032      // 64*112*1024
#define ROW     17           // padded LDS row (i64/f64 elems)

// ---- prepass (R24 verbatim): spikes -> A8 (b-major, kt-contiguous tiles);
//               W -> Bt 4 balanced base-256 i8 planes ----
__global__ __launch_bounds__(256)
void prepass(const float* __restrict__ S, const float* __restrict__ W,
             signed char* __restrict__ A8, signed char* __restrict__ Bt) {
    const int wave = blockIdx.x * 4 + (threadIdx.x >> 6);  // 0..8191
    const int lane = threadIdx.x & 63;
    const int r16 = lane & 15, quad = lane >> 4;

    if (wave < 7168) {
        // A tile: wave = b*112 + jt*16 + k64 ; rows t = jt*16 + r16
        const int b   = wave / 112;
        const int rem = wave - b * 112;
        const int jt  = rem >> 4, k64 = rem & 15;
        const int t   = jt * 16 + r16;
        union { signed char c[16]; int4v v; } u;
        if (t < T_STEPS) {
            const float* sp = S + ((size_t)t * 64 + b) * K_DIM + k64 * 64 + quad * 16;
            const float4 s0 = *(const float4*)(sp);
            const float4 s1 = *(const float4*)(sp + 4);
            const float4 s2 = *(const float4*)(sp + 8);
            const float4 s3 = *(const float4*)(sp + 12);
            const float sv[16] = {s0.x,s0.y,s0.z,s0.w, s1.x,s1.y,s1.z,s1.w,
                                  s2.x,s2.y,s2.z,s2.w, s3.x,s3.y,s3.z,s3.w};
#pragma unroll
            for (int e = 0; e < 16; ++e) u.c[e] = (signed char)sv[e];  // exact 0/1
        } else {
#pragma unroll
            for (int e = 0; e < 16; ++e) u.c[e] = 0;                   // t-pad
        }
        // kt-contiguous chunk index: k64*7 + jt
        *(int4v*)(A8 + ((size_t)(b * 112 + k64 * 7 + jt)) * 1024 + lane * 16) = u.v;
    } else {
        const int t2 = wave - 7168;                 // 0..1023
        const int n16 = t2 >> 4, k64 = t2 & 15;
        const int n = n16 * 16 + r16;
        const float* wp = W + (size_t)n * K_DIM + k64 * 64 + quad * 16;
        const float4 w0 = *(const float4*)(wp);
        const float4 w1 = *(const float4*)(wp + 4);
        const float4 w2 = *(const float4*)(wp + 8);
        const float4 w3 = *(const float4*)(wp + 12);
        const float wv[16] = {w0.x,w0.y,w0.z,w0.w, w1.x,w1.y,w1.z,w1.w,
                              w2.x,w2.y,w2.z,w2.w, w3.x,w3.y,w3.z,w3.w};
        union { signed char c[16]; int4v v; } u[4];
#pragma unroll
        for (int e = 0; e < 16; ++e) {
            long long q = llrint((double)wv[e] * 0x1p28);   // |q| < 2^31
#pragma unroll
            for (int p = 0; p < 3; ++p) {
                const int d = (int)(((q + 128) & 255) - 128);  // [-128,127]
                u[p].c[e] = (signed char)d;
                q = (q - d) >> 8;                              // exact
            }
            u[3].c[e] = (signed char)q;                        // |d3| <= ~88
        }
        signed char* base = Bt + (size_t)(n16 * 16 + k64) * 4 * 1024 + lane * 16;
#pragma unroll
        for (int p = 0; p < 4; ++p)
            *(int4v*)(base + (size_t)p * 1024) = u[p].v;
    }
}

// two MFMAs of one A fragment against both live planes
#define MM(I, AREG)                                                           \
    acc[I][0] = __builtin_amdgcn_mfma_i32_16x16x64_i8(AREG, b0, acc[I][0], 0, 0, 0); \
    acc[I][1] = __builtin_amdgcn_mfma_i32_16x16x64_i8(AREG, b1, acc[I][1], 0, 0, 0);

// ---- fused GEMM + scan: 2 waves/block, plane-split, 3 waves/SIMD. ----
__global__ __launch_bounds__(128, 3)
void gemm_scan(const signed char* __restrict__ A8,
               const signed char* __restrict__ Bt,
               const float* __restrict__ bias,
               const float* __restrict__ mem0,
               float* __restrict__ out) {
    __shared__ double dulds[T_STEPS * ROW];      // 13600 B; aliased i64 partials
    long long* llds = (long long*)dulds;

    const int bid = blockIdx.x;                  // 0..4095
    const int ng  = bid >> 6;                    // n16 tile 0..63
    const int b   = bid & 63;                    // bid%8 = b%8 -> XCD A-locality

    const int tid  = threadIdx.x;
    const int lane = tid & 63, wid = tid >> 6;   // wid w: planes {2w,2w+1}
    const int quad = lane >> 4, r16 = lane & 15;

    const signed char* abase = A8 + (size_t)b * T_PAD * 1024 + lane * 16;
    const signed char* bbase = Bt + (size_t)ng * 65536 + (size_t)wid * 2048 + lane * 16;

    int4v acc[7][2] = {};

    for (int kt = 0; kt < 16; ++kt) {
        const signed char* ak  = abase + (size_t)kt * 7168;
        const signed char* ak2 = ak + 4096;
        const signed char* bk  = bbase + (size_t)kt * 4096;
        const int4v b0 = *(const int4v*)(bk);
        const int4v b1 = *(const int4v*)(bk + 1024);
        int4v a0, a1;
        a0 = *(const int4v*)(ak);
        a1 = *(const int4v*)(ak + 1024);
        MM(0, a0);
        a0 = *(const int4v*)(ak + 2048);
        MM(1, a1);
        a1 = *(const int4v*)(ak + 3072);
        MM(2, a0);
        a0 = *(const int4v*)(ak2);
        MM(3, a1);
        a1 = *(const int4v*)(ak2 + 1024);
        MM(4, a0);
        a0 = *(const int4v*)(ak2 + 2048);
        MM(5, a1);
        MM(6, a0);
    }

    // partial Horner: wave1 stages v1 = d2 + 256*d3 (exact i64, padded rows)
    if (wid == 1) {
#pragma unroll
        for (int i = 0; i < 7; ++i)
#pragma unroll
            for (int e = 0; e < 4; ++e) {
                const int t = i * 16 + quad * 4 + e;
                if (t < T_STEPS)
                    llds[t * ROW + r16] =
                        (long long)acc[i][1][e] * 256 + (long long)acc[i][0][e];
            }
    }
    __syncthreads();
    if (wid == 0) {
        const double bd = (double)bias[ng * 16 + r16];
#pragma unroll
        for (int i = 0; i < 7; ++i)
#pragma unroll
            for (int e = 0; e < 4; ++e) {
                const int t = i * 16 + quad * 4 + e;
                if (t < T_STEPS) {
                    long long v =
                        (long long)acc[i][1][e] * 256 + (long long)acc[i][0][e];
                    v += llds[t * ROW + r16] << 16;     // + 2^16*(d2+256*d3)
                    dulds[t * ROW + r16] = (double)v * 0x1p-28 + bd;  // exact
                }
            }
    }
    __syncthreads();

    // membrane scan (R16 math verbatim, exact f64 du): wave0 lanes 0-15.
    if (wid == 0 && lane < 16) {
        const int bo = b * 1024 + ng * 16 + lane;
        double m = (double)mem0[bo];
        double cnt = 0.0;
        double d[4];
#pragma unroll
        for (int u = 0; u < 4; ++u) d[u] = dulds[u * ROW + lane];
        for (int g = 0; g < 25; ++g) {
            double dn[4];
            if (g + 1 < 25) {
#pragma unroll
                for (int u = 0; u < 4; ++u) dn[u] = dulds[((g + 1) * 4 + u) * ROW + lane];
            }
#pragma unroll
            for (int u = 0; u < 4; ++u) {
                m += d[u];
                const double s = (m > 15.0) ? 1.0 : 0.0;
                m = fmin(fmax(m, 0.0), 15.0);
                out[(size_t)(g * 4 + u) * BO + bo] = (float)s;
                cnt += s;
                m -= m * s;
            }
            if (g + 1 < 25) {
#pragma unroll
                for (int u = 0; u < 4; ++u) d[u] = dn[u];
            }
        }
        out[(size_t)T_STEPS * BO + bo] = (float)m;
        out[(size_t)(T_STEPS + 1) * BO + bo] = (float)(cnt * 0.01);
    }
}

extern "C" void kernel_launch(void* const* d_in, const int* in_sizes, int n_in,
                              void* d_out, int out_size, void* d_ws, size_t ws_size,
                              hipStream_t stream) {
    const float* spikes = (const float*)d_in[0];  // [100,64,1024]
    const float* mem    = (const float*)d_in[1];  // [64,1024]
    // d_in[2] = hat_spikes: dead in forward
    const float* W      = (const float*)d_in[3];  // [1024,1024]
    const float* b      = (const float*)d_in[4];  // [1024]
    float* out = (float*)d_out;
    signed char* A8 = (signed char*)d_ws + A8_OFF;
    signed char* Bt = (signed char*)d_ws + BT_OFF;

    prepass<<<dim3(2048), 256, 0, stream>>>(spikes, W, A8, Bt);
    gemm_scan<<<dim3(4096), 128, 0, stream>>>(A8, Bt, b, mem, out);
}

// Round 11
// 124.431 us; speedup vs baseline: 1.3676x; 1.1682x over previous
//
#include <hip/hip_runtime.h>

// SNNLinear, exact-trajectory i8-digit MFMA. Round 29 = fused kernel with
// R18's LDS A-dedup economics.
// Model (R21-R28 evidence): per-SIMD MFMA demand is 1142 cyc/kt -- latency
// is hideable; the binder in R21 was L2->CU PORT traffic (1.4 MB/CU/gen
// ~= 18us). R28's ping-pong additionally destroyed MLP (2 loads in
// flight). Occupancy pushes all spilled (allocator splits cap/2).
// R29: block = 4 waves x one (b, 64-col) task, 112m x 64n x 1024k x 4pl:
//   - A panel staged to LDS ONCE per block (dedup x4): reg-staged
//     issue-early/write-late (T14), double-buffered, 1 barrier/kt.
//     Wave w stages chunks {w, w+4(if w<3)}.
//   - B register-prefetched one kt ahead (bc/bn, static indices).
//   - acc[7][4]=112 at __launch_bounds__(256,2): proven R21/R22 register
//     class (acc 112<=128 acc-half, arch ~84<=128) -- no spill.
//   - du stored hi-f32 / lo-f16*4096 in LDS (exactly R18's PASSING
//     representation; same exact i64 Horner v, same f64 bias-add).
//     LDS total 54 KB -> 2 blocks/CU resident: one block's scan tail
//     overlaps the other's GEMM.
//   - scan: wave 0, 64 lanes = 64 cols, R16/R21-verbatim f64 math on
//     du = hi + lo*2^-12.
// Per-CU traffic 736 KB/gen (~4.8us port) < MFMA floor 7.6us/gen ->
// compute-bound at last.
// Outputs: ss[100,64,1024] | mem_out[64,1024] | hat_s[64,1024]
// ws: [0, 7.34M) A8 (b-major, kt-contiguous) ; [7.34M, 11.53M) Bt (4 planes)

typedef __attribute__((ext_vector_type(4))) int int4v;

#define T_STEPS 100
#define T_PAD   112
#define BO      65536
#define K_DIM   1024
#define A8_OFF  0
#define BT_OFF  7340032      // 64*112*1024

// ---- prepass (R28 verbatim): spikes -> A8 (b-major, kt-contiguous tiles);
//               W -> Bt 4 balanced base-256 i8 planes ----
__global__ __launch_bounds__(256)
void prepass(const float* __restrict__ S, const float* __restrict__ W,
             signed char* __restrict__ A8, signed char* __restrict__ Bt) {
    const int wave = blockIdx.x * 4 + (threadIdx.x >> 6);  // 0..8191
    const int lane = threadIdx.x & 63;
    const int r16 = lane & 15, quad = lane >> 4;

    if (wave < 7168) {
        // A tile: wave = b*112 + jt*16 + k64 ; rows t = jt*16 + r16
        const int b   = wave / 112;
        const int rem = wave - b * 112;
        const int jt  = rem >> 4, k64 = rem & 15;
        const int t   = jt * 16 + r16;
        union { signed char c[16]; int4v v; } u;
        if (t < T_STEPS) {
            const float* sp = S + ((size_t)t * 64 + b) * K_DIM + k64 * 64 + quad * 16;
            const float4 s0 = *(const float4*)(sp);
            const float4 s1 = *(const float4*)(sp + 4);
            const float4 s2 = *(const float4*)(sp + 8);
            const float4 s3 = *(const float4*)(sp + 12);
            const float sv[16] = {s0.x,s0.y,s0.z,s0.w, s1.x,s1.y,s1.z,s1.w,
                                  s2.x,s2.y,s2.z,s2.w, s3.x,s3.y,s3.z,s3.w};
#pragma unroll
            for (int e = 0; e < 16; ++e) u.c[e] = (signed char)sv[e];  // exact 0/1
        } else {
#pragma unroll
            for (int e = 0; e < 16; ++e) u.c[e] = 0;                   // t-pad
        }
        // kt-contiguous chunk index: k64*7 + jt
        *(int4v*)(A8 + ((size_t)(b * 112 + k64 * 7 + jt)) * 1024 + lane * 16) = u.v;
    } else {
        const int t2 = wave - 7168;                 // 0..1023
        const int n16 = t2 >> 4, k64 = t2 & 15;
        const int n = n16 * 16 + r16;
        const float* wp = W + (size_t)n * K_DIM + k64 * 64 + quad * 16;
        const float4 w0 = *(const float4*)(wp);
        const float4 w1 = *(const float4*)(wp + 4);
        const float4 w2 = *(const float4*)(wp + 8);
        const float4 w3 = *(const float4*)(wp + 12);
        const float wv[16] = {w0.x,w0.y,w0.z,w0.w, w1.x,w1.y,w1.z,w1.w,
                              w2.x,w2.y,w2.z,w2.w, w3.x,w3.y,w3.z,w3.w};
        union { signed char c[16]; int4v v; } u[4];
#pragma unroll
        for (int e = 0; e < 16; ++e) {
            long long q = llrint((double)wv[e] * 0x1p28);   // |q| < 2^31
#pragma unroll
            for (int p = 0; p < 3; ++p) {
                const int d = (int)(((q + 128) & 255) - 128);  // [-128,127]
                u[p].c[e] = (signed char)d;
                q = (q - d) >> 8;                              // exact
            }
            u[3].c[e] = (signed char)q;                        // |d3| <= ~88
        }
        signed char* base = Bt + (size_t)(n16 * 16 + k64) * 4 * 1024 + lane * 16;
#pragma unroll
        for (int p = 0; p < 4; ++p)
            *(int4v*)(base + (size_t)p * 1024) = u[p].v;
    }
}

// ---- fused GEMM + scan: 4 waves/block, LDS A-dedup, 2 blocks/CU. ----
__global__ __launch_bounds__(256, 2)
void gemm_scan(const signed char* __restrict__ A8,
               const signed char* __restrict__ Bt,
               const float* __restrict__ bias,
               const float* __restrict__ mem0,
               float* __restrict__ out) {
    __shared__ __align__(16) signed char ldsA[2][7168];   // A kt-chunk dbuf
    __shared__ float    hilds[T_STEPS][66];               // du hi (f32)
    __shared__ _Float16 lolds[T_STEPS][66];               // du lo * 4096 (f16)

    const int bid = blockIdx.x;                  // 0..1023
    const int ngg = bid >> 6;                    // 64-col group 0..15
    const int b   = bid & 63;                    // bid%8 = b%8 -> XCD locality

    const int tid  = threadIdx.x;
    const int lane = tid & 63, wid = tid >> 6;   // wave = n16 tile 0..3
    const int quad = lane >> 4, r16 = lane & 15;

    const signed char* apan  = A8 + (size_t)b * (T_PAD * 1024) + lane * 16;
    const signed char* bbase = Bt + (size_t)(ngg * 4 + wid) * 65536 + lane * 16;

    int4v acc[7][4] = {};
    int4v bc[4], bn[4], stg0, stg1;

    // staging: wave w owns chunks {w, w+4 if w<3} of each 7-chunk kt tile
#define STG_LOAD(KT)                                                          \
    {                                                                         \
        stg0 = *(const int4v*)(apan + ((size_t)(KT) * 7 + wid) * 1024);       \
        if (wid < 3)                                                          \
            stg1 = *(const int4v*)(apan + ((size_t)(KT) * 7 + wid + 4) * 1024); \
    }
#define STG_WRITE(BUF)                                                        \
    {                                                                         \
        *(int4v*)(&ldsA[BUF][wid * 1024 + lane * 16]) = stg0;                 \
        if (wid < 3)                                                          \
            *(int4v*)(&ldsA[BUF][(wid + 4) * 1024 + lane * 16]) = stg1;       \
    }

    // prologue: stage kt=0, load B kt=0
    STG_LOAD(0);
    STG_WRITE(0);
#pragma unroll
    for (int p = 0; p < 4; ++p) bc[p] = *(const int4v*)(bbase + (size_t)p * 1024);
    __syncthreads();

    for (int kt = 0; kt < 16; ++kt) {
        const int cur = kt & 1, nxt = cur ^ 1;
        if (kt + 1 < 16) {                       // issue-early (T14)
            STG_LOAD(kt + 1);
#pragma unroll
            for (int p = 0; p < 4; ++p)
                bn[p] = *(const int4v*)(bbase + (size_t)((kt + 1) * 4 + p) * 1024);
        }
        int4v af[7];
#pragma unroll
        for (int i = 0; i < 7; ++i)
            af[i] = *(const int4v*)(&ldsA[cur][i * 1024 + lane * 16]);
#pragma unroll
        for (int p = 0; p < 4; ++p)
#pragma unroll
            for (int i = 0; i < 7; ++i)
                acc[i][p] = __builtin_amdgcn_mfma_i32_16x16x64_i8(
                    af[i], bc[p], acc[i][p], 0, 0, 0);
        if (kt + 1 < 16) {                       // write-late (T14)
            STG_WRITE(nxt);
#pragma unroll
            for (int p = 0; p < 4; ++p) bc[p] = bn[p];
        }
        __syncthreads();
    }

    // exact i64 Horner -> f64 du -> hi/lo LDS (R18's passing representation)
    const int cb = wid * 16 + r16;               // col 0..63
    const double bd = (double)bias[ngg * 64 + cb];
#pragma unroll
    for (int i = 0; i < 7; ++i)
#pragma unroll
        for (int e = 0; e < 4; ++e) {
            const int t = i * 16 + quad * 4 + e;
            if (t < T_STEPS) {
                long long v = (long long)acc[i][3][e];
                v = v * 256 + (long long)acc[i][2][e];
                v = v * 256 + (long long)acc[i][1][e];
                v = v * 256 + (long long)acc[i][0][e];   // exact, |v| < 2^42
                const double du = (double)v * 0x1p-28 + bd;
                const float hi = (float)du;
                hilds[t][cb] = hi;
                lolds[t][cb] = (_Float16)((float)(du - (double)hi) * 4096.0f);
            }
        }
    __syncthreads();

    // membrane scan (R16 math verbatim, du = hi + lo*2^-12): wave 0, 64 cols.
    if (wid == 0) {
        const int bo = b * 1024 + ngg * 64 + lane;
        double m = (double)mem0[bo];
        double cnt = 0.0;
        double d[4];
#pragma unroll
        for (int u = 0; u < 4; ++u)
            d[u] = (double)hilds[u][lane] + (double)(float)lolds[u][lane] * 0x1p-12;
        for (int g = 0; g < 25; ++g) {
            double dn[4];
            if (g + 1 < 25) {
#pragma unroll
                for (int u = 0; u < 4; ++u) {
                    const int tt = (g + 1) * 4 + u;
                    dn[u] = (double)hilds[tt][lane]
                          + (double)(float)lolds[tt][lane] * 0x1p-12;
                }
            }
#pragma unroll
            for (int u = 0; u < 4; ++u) {
                m += d[u];
                const double s = (m > 15.0) ? 1.0 : 0.0;
                m = fmin(fmax(m, 0.0), 15.0);
                out[(size_t)(g * 4 + u) * BO + bo] = (float)s;
                cnt += s;
                m -= m * s;
            }
            if (g + 1 < 25) {
#pragma unroll
                for (int u = 0; u < 4; ++u) d[u] = dn[u];
            }
        }
        out[(size_t)T_STEPS * BO + bo] = (float)m;
        out[(size_t)(T_STEPS + 1) * BO + bo] = (float)(cnt * 0.01);
    }
}

extern "C" void kernel_launch(void* const* d_in, const int* in_sizes, int n_in,
                              void* d_out, int out_size, void* d_ws, size_t ws_size,
                              hipStream_t stream) {
    const float* spikes = (const float*)d_in[0];  // [100,64,1024]
    const float* mem    = (const float*)d_in[1];  // [64,1024]
    // d_in[2] = hat_spikes: dead in forward
    const float* W      = (const float*)d_in[3];  // [1024,1024]
    const float* b      = (const float*)d_in[4];  // [1024]
    float* out = (float*)d_out;
    signed char* A8 = (signed char*)d_ws + A8_OFF;
    signed char* Bt = (signed char*)d_ws + BT_OFF;

    prepass<<<dim3(2048), 256, 0, stream>>>(spikes, W, A8, Bt);
    gemm_scan<<<dim3(1024), 256, 0, stream>>>(A8, Bt, b, mem, out);
}